// Round 15
// baseline (249.689 us; speedup 1.0000x reference)
//
#include <hip/hip_runtime.h>
#include <math.h>

#define N_NODES 50000
#define N_EDGES 800000
#define N_STRIPS 3125     // 50000 / 16
#define N_BUCKETS 196     // ceil(50000/256); bucket = dst>>8
#define CAP_B 6144        // fixed records per bucket segment
#define CHUNK_A 2048      // edges per fillA block
#define FILLA_BLOCKS 391  // ceil(800000/2048)
#define PROJ_BLOCKS 12500 // 50000*64/256

typedef __attribute__((ext_vector_type(8))) short bf16x8;
typedef __attribute__((ext_vector_type(4))) float f32x4;
typedef __attribute__((ext_vector_type(2))) float f32x2;

// ---------- helpers ----------
__device__ __forceinline__ unsigned short f2bf(float f) {  // RNE f32->bf16
  unsigned int u = __float_as_uint(f);
  u += 0x7FFFu + ((u >> 16) & 1u);
  return (unsigned short)(u >> 16);
}
__device__ __forceinline__ unsigned char f2fp8(float f) {  // e4m3fn (OCP) encode
  return (unsigned char)(__builtin_amdgcn_cvt_pk_fp8_f32(f, f, 0, false) & 0xFF);
}

// ---------- 1. fused: fillA (blocks [0,391)) + input projection (rest) ----------
// 8B buf1 record: x = src(17) | q0(13)<<17 | (dl&3)<<30 ; y = q1(13) | q2(13)<<13 | (dl>>2)<<26
__global__ __launch_bounds__(256) void k_pre(const int* __restrict__ ei,
                                             const float* __restrict__ ea,
                                             const float* __restrict__ ew1,
                                             const float* __restrict__ eb1,
                                             const float* __restrict__ ew2,
                                             const float* __restrict__ eb2,
                                             int* __restrict__ bcur,
                                             uint2* __restrict__ buf1,
                                             const float* __restrict__ x,
                                             const float* __restrict__ Wp,
                                             const float* __restrict__ bp,
                                             unsigned short* __restrict__ hb,
                                             unsigned char* __restrict__ h8) {
  __shared__ int lcnt[N_BUCKETS];
  __shared__ int gb[N_BUCKETS];
  if (blockIdx.x >= FILLA_BLOCKS) {
    // ---- projection half ----
    int idx = (blockIdx.x - FILLA_BLOCKS) * 256 + threadIdx.x;
    int n = idx >> 6, j = idx & 63;
    float acc = bp[j];
#pragma unroll
    for (int k = 0; k < 10; k++) acc += __builtin_nontemporal_load(&x[n * 10 + k]) * Wp[k * 64 + j];
    float r = fmaxf(acc, 0.f);
    hb[n * 64 + j] = f2bf(r);
    h8[n * 64 + j] = f2fp8(r);
    return;
  }
  // ---- fillA half ----
  for (int i = threadIdx.x; i < N_BUCKETS; i += 256) lcnt[i] = 0;
  __syncthreads();
  int base = blockIdx.x * CHUNK_A;
  uint2 rec[CHUNK_A / 256];
  int bk[CHUNK_A / 256], rk[CHUNK_A / 256];
#pragma unroll
  for (int k = 0; k < CHUNK_A / 256; k++) {
    int e = base + k * 256 + threadIdx.x;
    bk[k] = -1;
    if (e < N_EDGES) {
      int s = __builtin_nontemporal_load(&ei[e]);
      int d = __builtin_nontemporal_load(&ei[N_EDGES + e]);
      float a0 = __builtin_nontemporal_load(&ea[e * 3 + 0]);
      float a1 = __builtin_nontemporal_load(&ea[e * 3 + 1]);
      float a2 = __builtin_nontemporal_load(&ea[e * 3 + 2]);
      int q[3];
#pragma unroll
      for (int l = 0; l < 3; l++) {
        float z = eb2[l];
#pragma unroll
        for (int t = 0; t < 16; t++) {
          float hd = a0 * ew1[l * 48 + t] + a1 * ew1[l * 48 + 16 + t] +
                     a2 * ew1[l * 48 + 32 + t] + eb1[l * 16 + t];
          z += fmaxf(hd, 0.f) * ew2[l * 16 + t];
        }
        float w = 1.f / (1.f + __expf(-z));
        q[l] = __float2int_rn(w * 8191.f);
      }
      unsigned int dl = (unsigned int)(d & 255);
      rec[k].x = (unsigned int)s | ((unsigned int)q[0] << 17) | ((dl & 3u) << 30);
      rec[k].y = (unsigned int)q[1] | ((unsigned int)q[2] << 13) | ((dl >> 2) << 26);
      int b = d >> 8;
      bk[k] = b;
      rk[k] = atomicAdd(&lcnt[b], 1);
    }
  }
  __syncthreads();
  if (threadIdx.x < N_BUCKETS) {
    int c = lcnt[threadIdx.x];
    gb[threadIdx.x] = threadIdx.x * CAP_B + (c ? atomicAdd(&bcur[threadIdx.x], c) : 0);
  }
  __syncthreads();
#pragma unroll
  for (int k = 0; k < CHUNK_A / 256; k++)
    if (bk[k] >= 0) buf1[gb[bk[k]] + rk[k]] = rec[k];
}

// ---------- 2. fillB: block = bucket; LDS histogram + scan -> per-dst offsets,
// scatter into 3 per-layer 4B weight planes (src(17) | q13<<17);
// per-bucket degree-class-grouped node order. buf1 read twice -> cached loads.
__global__ __launch_bounds__(256) void k_fillB(const uint2* __restrict__ buf1,
                                               const int* __restrict__ bcur,
                                               unsigned int* __restrict__ pl0,
                                               unsigned int* __restrict__ pl1,
                                               unsigned int* __restrict__ pl2,
                                               int* __restrict__ aoffs,
                                               int* __restrict__ adeg,
                                               int* __restrict__ order) {
  __shared__ int lhist[256];
  __shared__ int lscan[256];
  __shared__ int lcls[8];
  __shared__ int lbase[8];
  int b = blockIdx.x;
  int t = threadIdx.x;
  int segbase = b * CAP_B;
  int cnt = bcur[b];
  lhist[t] = 0;
  if (t < 8) lcls[t] = 0;
  __syncthreads();
  for (int i = t; i < cnt; i += 256) {
    uint2 rec = buf1[segbase + i];
    int dl = (int)((rec.x >> 30) | (((rec.y >> 26) & 63u) << 2));
    atomicAdd(&lhist[dl], 1);
  }
  __syncthreads();
  int v = lhist[t];
  lscan[t] = v;
  __syncthreads();
#pragma unroll
  for (int off = 1; off < 256; off <<= 1) {
    int u = (t >= off) ? lscan[t - off] : 0;
    __syncthreads();
    lscan[t] += u;
    __syncthreads();
  }
  int excl = lscan[t] - v;
  int nid = b * 256 + t;
  int cls = 0, rank = 0;
  bool valid = nid < N_NODES;
  if (valid) {
    aoffs[nid] = segbase + excl;
    adeg[nid] = v;
    cls = min(v >> 2, 7);
    rank = atomicAdd(&lcls[cls], 1);
  }
  __syncthreads();
  if (t == 0) {
    int acc2 = 0;
#pragma unroll
    for (int c = 0; c < 8; c++) { lbase[c] = acc2; acc2 += lcls[c]; }
  }
  lhist[t] = segbase + excl;  // reuse as write cursor
  __syncthreads();
  if (valid) order[b * 256 + lbase[cls] + rank] = nid;
  for (int i = t; i < cnt; i += 256) {
    uint2 rec = buf1[segbase + i];
    int dl = (int)((rec.x >> 30) | (((rec.y >> 26) & 63u) << 2));
    int pos = atomicAdd(&lhist[dl], 1);
    unsigned int src = rec.x & 0x1FFFFu;
    pl0[pos] = src | ((rec.x >> 17) & 0x1FFFu) << 17;
    pl1[pos] = src | (rec.y & 0x1FFFu) << 17;
    pl2[pos] = src | ((rec.y >> 13) & 0x1FFFu) << 17;
  }
}

// ---------- 3. fused layer: per-strip agg (node-local!) + MFMA mlp [+ head] ----------
// Strip = 16 nodes from order[] (degree-class grouped). Phase A aggregates into a
// per-wave LDS tile; phase B runs the MFMA mlp with A = [hb rows | LDS tile].
// C/D layout: col=lane&15, row=(lane>>4)*4+reg ; A/B frag: k=(lane>>4)*8+j
template <bool HEAD>
__global__ __launch_bounds__(256, 3) void k_layer(
    const unsigned int* __restrict__ pl,
    const int* __restrict__ aoffs,
    const int* __restrict__ adeg,
    const int* __restrict__ order,
    const unsigned char* __restrict__ h8in,
    const unsigned short* __restrict__ hb_in,
    const float* __restrict__ nw, const float* __restrict__ nb,
    const float* __restrict__ g, const float* __restrict__ b,
    unsigned short* __restrict__ hbout, unsigned char* __restrict__ h8out,
    const float* __restrict__ hw1, const float* __restrict__ hb1,
    const float* __restrict__ hw2, const float* __restrict__ hb2,
    float* __restrict__ out) {
  __shared__ unsigned short lt[4][16 * 72];  // per-wave tile, short-stride 72
  int lane = threadIdx.x & 63;
  int n16 = lane & 15;
  int q = lane >> 4;
  int sub = lane >> 3;   // agg: node slot 0..7
  int jj = lane & 7;     // agg: feature octet
  int wv = threadIdx.x >> 6;
  int wid = (blockIdx.x * 256 + threadIdx.x) >> 6;
  int nwaves = gridDim.x * 4;

  bf16x8 bfr[4][4];
#pragma unroll
  for (int t = 0; t < 4; t++)
#pragma unroll
    for (int kc = 0; kc < 4; kc++) {
      bf16x8 v;
#pragma unroll
      for (int j2 = 0; j2 < 8; j2++) {
        int k = kc * 32 + q * 8 + j2;
        v[j2] = (short)f2bf(nw[k * 64 + t * 16 + n16]);
      }
      bfr[t][kc] = v;
    }
  bf16x8 eye[2];  // identity selector: E_p[k][n] = (k == n+16p)
#pragma unroll
  for (int p = 0; p < 2; p++) {
    bf16x8 v;
#pragma unroll
    for (int j2 = 0; j2 < 8; j2++)
      v[j2] = ((q * 8 + j2) == (n16 + 16 * p)) ? (short)0x3F80 : (short)0;
    eye[p] = v;
  }
  float nbv[4], gv[4], bv[4];
#pragma unroll
  for (int t = 0; t < 4; t++) {
    nbv[t] = nb[t * 16 + n16];
    gv[t] = g[t * 16 + n16];
    bv[t] = b[t * 16 + n16];
  }
  bf16x8 hfr[2][2];
  float hb1v[2], hw2v[2], hb2v = 0.f;
  if (HEAD) {
#pragma unroll
    for (int kc = 0; kc < 2; kc++)
#pragma unroll
      for (int tl = 0; tl < 2; tl++) {
        bf16x8 v;
#pragma unroll
        for (int j2 = 0; j2 < 8; j2++)
          v[j2] = (short)f2bf(hw1[(kc * 32 + q * 8 + j2) * 32 + tl * 16 + n16]);
        hfr[kc][tl] = v;
      }
#pragma unroll
    for (int tl = 0; tl < 2; tl++) {
      hb1v[tl] = hb1[tl * 16 + n16];
      hw2v[tl] = hw2[tl * 16 + n16];
    }
    hb2v = hb2[0];
  }

  const uint2* hrow = (const uint2*)h8in;  // gather row n at hrow[n*8 + jj]

  for (int s = wid; s < N_STRIPS; s += nwaves) {
    // ---- phase A: aggregate 16 nodes (2 halves of 8), bf16 -> LDS tile ----
#pragma unroll
    for (int half = 0; half < 2; half++) {
      int n = order[s * 16 + half * 8 + sub];
      int start = aoffs[n];
      int d = adeg[n];
      float a0 = 0.f, a1 = 0.f, a2 = 0.f, a3 = 0.f;
      float a4 = 0.f, a5 = 0.f, a6 = 0.f, a7 = 0.f, ws = 0.f;
      int i = 0;
      if (d >= 4) {
        unsigned int c0 = pl[start + 0], c1 = pl[start + 1];
        unsigned int c2 = pl[start + 2], c3 = pl[start + 3];
        for (;;) {
          int nxt = i + 4;
          bool more = (nxt + 4 <= d);
          unsigned int m0, m1, m2, m3;
          if (more) {
            m0 = pl[start + nxt + 0]; m1 = pl[start + nxt + 1];
            m2 = pl[start + nxt + 2]; m3 = pl[start + nxt + 3];
          }
          uint2 g0 = hrow[(c0 & 0x1FFFFu) * 8 + jj];
          uint2 g1 = hrow[(c1 & 0x1FFFFu) * 8 + jj];
          uint2 g2 = hrow[(c2 & 0x1FFFFu) * 8 + jj];
          uint2 g3 = hrow[(c3 & 0x1FFFFu) * 8 + jj];
          float w0 = (float)(c0 >> 17) * (1.f / 8191.f);
          float w1 = (float)(c1 >> 17) * (1.f / 8191.f);
          float w2 = (float)(c2 >> 17) * (1.f / 8191.f);
          float w3 = (float)(c3 >> 17) * (1.f / 8191.f);
#pragma unroll
          for (int k = 0; k < 4; k++) {
            uint2 gg = (k == 0) ? g0 : (k == 1) ? g1 : (k == 2) ? g2 : g3;
            float w = (k == 0) ? w0 : (k == 1) ? w1 : (k == 2) ? w2 : w3;
            f32x2 p01 = __builtin_amdgcn_cvt_pk_f32_fp8(gg.x, false);
            f32x2 p23 = __builtin_amdgcn_cvt_pk_f32_fp8(gg.x, true);
            f32x2 p45 = __builtin_amdgcn_cvt_pk_f32_fp8(gg.y, false);
            f32x2 p67 = __builtin_amdgcn_cvt_pk_f32_fp8(gg.y, true);
            a0 += p01[0] * w; a1 += p01[1] * w;
            a2 += p23[0] * w; a3 += p23[1] * w;
            a4 += p45[0] * w; a5 += p45[1] * w;
            a6 += p67[0] * w; a7 += p67[1] * w;
          }
          ws += w0 + w1 + w2 + w3;
          i = nxt;
          if (!more) break;
          c0 = m0; c1 = m1; c2 = m2; c3 = m3;
        }
      }
      for (; i < d; ++i) {
        unsigned int c = pl[start + i];
        uint2 gg = hrow[(c & 0x1FFFFu) * 8 + jj];
        float w = (float)(c >> 17) * (1.f / 8191.f);
        f32x2 p01 = __builtin_amdgcn_cvt_pk_f32_fp8(gg.x, false);
        f32x2 p23 = __builtin_amdgcn_cvt_pk_f32_fp8(gg.x, true);
        f32x2 p45 = __builtin_amdgcn_cvt_pk_f32_fp8(gg.y, false);
        f32x2 p67 = __builtin_amdgcn_cvt_pk_f32_fp8(gg.y, true);
        a0 += p01[0] * w; a1 += p01[1] * w;
        a2 += p23[0] * w; a3 += p23[1] * w;
        a4 += p45[0] * w; a5 += p45[1] * w;
        a6 += p67[0] * w; a7 += p67[1] * w;
        ws += w;
      }
      float inv = 1.f / fmaxf(ws, 1e-12f);
      unsigned int u0 = (unsigned int)f2bf(a0 * inv) | ((unsigned int)f2bf(a1 * inv) << 16);
      unsigned int u1 = (unsigned int)f2bf(a2 * inv) | ((unsigned int)f2bf(a3 * inv) << 16);
      unsigned int u2 = (unsigned int)f2bf(a4 * inv) | ((unsigned int)f2bf(a5 * inv) << 16);
      unsigned int u3 = (unsigned int)f2bf(a6 * inv) | ((unsigned int)f2bf(a7 * inv) << 16);
      unsigned int* dst = (unsigned int*)&lt[wv][(half * 8 + sub) * 72 + jj * 8];
      dst[0] = u0; dst[1] = u1; dst[2] = u2; dst[3] = u3;
    }
    asm volatile("s_waitcnt lgkmcnt(0)" ::: "memory");  // wave-local LDS RAW
    // ---- phase B: MFMA mlp on the permuted strip ----
    int ordn = order[s * 16 + n16];  // A row n16's node
    f32x4 acc[4] = {{0.f, 0.f, 0.f, 0.f}, {0.f, 0.f, 0.f, 0.f},
                    {0.f, 0.f, 0.f, 0.f}, {0.f, 0.f, 0.f, 0.f}};
    bf16x8 afr[4];
#pragma unroll
    for (int kc = 0; kc < 4; kc++) {
      if (kc < 2)
        afr[kc] = __builtin_nontemporal_load(
            (const bf16x8*)(hb_in + (size_t)ordn * 64 + (kc & 1) * 32 + q * 8));
      else
        afr[kc] = *(const bf16x8*)&lt[wv][n16 * 72 + (kc & 1) * 32 + q * 8];
#pragma unroll
      for (int t = 0; t < 4; t++)
        acc[t] = __builtin_amdgcn_mfma_f32_16x16x32_bf16(afr[kc], bfr[t][kc], acc[t], 0, 0, 0);
    }
    f32x4 rres[4];  // residual h in C layout via identity MFMA (exact)
#pragma unroll
    for (int t = 0; t < 4; t++) {
      f32x4 z = {0.f, 0.f, 0.f, 0.f};
      rres[t] = __builtin_amdgcn_mfma_f32_16x16x32_bf16(afr[t >> 1], eye[t & 1], z, 0, 0, 0);
    }
    float r[4][4];
    float p[4], p2[4];
#pragma unroll
    for (int rg = 0; rg < 4; rg++) { p[rg] = 0.f; p2[rg] = 0.f; }
#pragma unroll
    for (int t = 0; t < 4; t++)
#pragma unroll
      for (int rg = 0; rg < 4; rg++) {
        float rr = rres[t][rg] + fmaxf(acc[t][rg] + nbv[t], 0.f);
        r[t][rg] = rr;
        p[rg] += rr;
        p2[rg] += rr * rr;
      }
#pragma unroll
    for (int rg = 0; rg < 4; rg++)
#pragma unroll
      for (int off = 1; off < 16; off <<= 1) {
        p[rg] += __shfl_xor(p[rg], off);
        p2[rg] += __shfl_xor(p2[rg], off);
      }
    int rnode[4];
#pragma unroll
    for (int rg = 0; rg < 4; rg++) rnode[rg] = order[s * 16 + q * 4 + rg];
#pragma unroll
    for (int rg = 0; rg < 4; rg++) {
      float mu = p[rg] * (1.f / 64.f);
      float var = p2[rg] * (1.f / 64.f) - mu * mu;
      float rs = rsqrtf(fmaxf(var, 0.f) + 1e-5f);
      int row = rnode[rg];
#pragma unroll
      for (int t = 0; t < 4; t++) {
        float o = (r[t][rg] - mu) * rs * gv[t] + bv[t];
        unsigned short ob = f2bf(o);
        hbout[row * 64 + t * 16 + n16] = ob;
        h8out[row * 64 + t * 16 + n16] = f2fp8(o);
        if (HEAD) lt[wv][(q * 4 + rg) * 72 + t * 16 + n16] = ob;
      }
    }
    if (HEAD) {
      asm volatile("s_waitcnt lgkmcnt(0)" ::: "memory");
      f32x4 hacc[2] = {{0.f, 0.f, 0.f, 0.f}, {0.f, 0.f, 0.f, 0.f}};
#pragma unroll
      for (int kc = 0; kc < 2; kc++) {
        bf16x8 ha = *(const bf16x8*)&lt[wv][n16 * 72 + kc * 32 + q * 8];
#pragma unroll
        for (int tl = 0; tl < 2; tl++)
          hacc[tl] = __builtin_amdgcn_mfma_f32_16x16x32_bf16(ha, hfr[kc][tl], hacc[tl], 0, 0, 0);
      }
#pragma unroll
      for (int rg = 0; rg < 4; rg++) {
        float sres = fmaxf(hacc[0][rg] + hb1v[0], 0.f) * hw2v[0] +
                     fmaxf(hacc[1][rg] + hb1v[1], 0.f) * hw2v[1];
#pragma unroll
        for (int off = 1; off < 16; off <<= 1) sres += __shfl_xor(sres, off);
        if (n16 == 0) out[rnode[rg]] = sres + hb2v;
      }
    }
  }
}

// ---------- launch ----------
static inline size_t align256(size_t x) { return (x + 255) & ~size_t(255); }

extern "C" void kernel_launch(void* const* d_in, const int* in_sizes, int n_in,
                              void* d_out, int out_size, void* d_ws, size_t ws_size,
                              hipStream_t stream) {
  const float* x   = (const float*)d_in[0];
  const int*   ei  = (const int*)d_in[1];
  const float* ea  = (const float*)d_in[2];
  const float* Wp  = (const float*)d_in[3];
  const float* bp  = (const float*)d_in[4];
  const float* ew1 = (const float*)d_in[5];
  const float* eb1 = (const float*)d_in[6];
  const float* ew2 = (const float*)d_in[7];
  const float* eb2 = (const float*)d_in[8];
  const float* nw  = (const float*)d_in[9];
  const float* nb  = (const float*)d_in[10];
  const float* lng = (const float*)d_in[11];
  const float* lnb = (const float*)d_in[12];
  const float* hw1 = (const float*)d_in[13];
  const float* hb1 = (const float*)d_in[14];
  const float* hw2 = (const float*)d_in[15];
  const float* hb2 = (const float*)d_in[16];
  float* out = (float*)d_out;

  char* ws = (char*)d_ws;
  size_t off = 0;
  unsigned short* hb0  = (unsigned short*)(ws + off); off = align256(off + (size_t)N_NODES * 64 * 2);
  unsigned short* hb1b = (unsigned short*)(ws + off); off = align256(off + (size_t)N_NODES * 64 * 2);
  unsigned char* h8_0  = (unsigned char*)(ws + off); off = align256(off + (size_t)N_NODES * 64);
  unsigned char* h8_1  = (unsigned char*)(ws + off); off = align256(off + (size_t)N_NODES * 64);
  uint2* buf1 = (uint2*)(ws + off); off = align256(off + (size_t)N_BUCKETS * CAP_B * 8);
  unsigned int* pl0 = (unsigned int*)(ws + off); off = align256(off + (size_t)N_BUCKETS * CAP_B * 4);
  unsigned int* pl1 = (unsigned int*)(ws + off); off = align256(off + (size_t)N_BUCKETS * CAP_B * 4);
  unsigned int* pl2 = (unsigned int*)(ws + off); off = align256(off + (size_t)N_BUCKETS * CAP_B * 4);
  int* aoffs  = (int*)(ws + off); off = align256(off + (size_t)N_NODES * 4);
  int* adeg   = (int*)(ws + off); off = align256(off + (size_t)N_NODES * 4);
  int* order  = (int*)(ws + off); off = align256(off + (size_t)N_NODES * 4);
  int* bcur   = (int*)(ws + off); off = align256(off + 1024);

  (void)hipMemsetAsync(bcur, 0, N_BUCKETS * 4, stream);
  k_pre<<<FILLA_BLOCKS + PROJ_BLOCKS, 256, 0, stream>>>(ei, ea, ew1, eb1, ew2, eb2, bcur, buf1,
                                                        x, Wp, bp, hb0, h8_0);
  k_fillB<<<N_BUCKETS, 256, 0, stream>>>(buf1, bcur, pl0, pl1, pl2, aoffs, adeg, order);

  const int layerGrid = 782;  // 3128 waves >= 3125 strips

  // layer 0: hb0/h8_0 -> hb1b/h8_1
  k_layer<false><<<layerGrid, 256, 0, stream>>>(pl0, aoffs, adeg, order, h8_0, hb0,
                                                nw + 0 * 8192, nb + 0 * 64, lng + 0 * 64, lnb + 0 * 64,
                                                hb1b, h8_1, hw1, hb1, hw2, hb2, out);
  // layer 1: hb1b/h8_1 -> hb0/h8_0
  k_layer<false><<<layerGrid, 256, 0, stream>>>(pl1, aoffs, adeg, order, h8_1, hb1b,
                                                nw + 1 * 8192, nb + 1 * 64, lng + 1 * 64, lnb + 1 * 64,
                                                hb0, h8_0, hw1, hb1, hw2, hb2, out);
  // layer 2 + fused head: hb0/h8_0 -> hb1b/h8_1, writes out
  k_layer<true><<<layerGrid, 256, 0, stream>>>(pl2, aoffs, adeg, order, h8_0, hb0,
                                               nw + 2 * 8192, nb + 2 * 64, lng + 2 * 64, lnb + 2 * 64,
                                               hb1b, h8_1, hw1, hb1, hw2, hb2, out);
}

// Round 16
// 223.407 us; speedup vs baseline: 1.1176x; 1.1176x over previous
//
#include <hip/hip_runtime.h>
#include <math.h>

#define N_NODES 50000
#define N_EDGES 800000
#define N_STRIPS 3125     // 50000 / 16
#define N_BUCKETS 196     // ceil(50000/256); bucket = dst>>8
#define CAP_B 6144        // fixed records per bucket segment
#define CHUNK_A 2048      // edges per fillA block
#define FILLA_BLOCKS 391  // ceil(800000/2048)
#define PROJ_BLOCKS 12500 // 50000*64/256

typedef __attribute__((ext_vector_type(8))) short bf16x8;
typedef __attribute__((ext_vector_type(4))) float f32x4;
typedef __attribute__((ext_vector_type(2))) float f32x2;

// ---------- helpers ----------
__device__ __forceinline__ unsigned short f2bf(float f) {  // RNE f32->bf16
  unsigned int u = __float_as_uint(f);
  u += 0x7FFFu + ((u >> 16) & 1u);
  return (unsigned short)(u >> 16);
}
__device__ __forceinline__ unsigned char f2fp8(float f) {  // e4m3fn (OCP) encode
  return (unsigned char)(__builtin_amdgcn_cvt_pk_fp8_f32(f, f, 0, false) & 0xFF);
}

// ---------- 1. fused: fillA (blocks [0,391)) + input projection (rest) ----------
// 8B buf1 record: x = src(17) | q0(13)<<17 | (dl&3)<<30 ; y = q1(13) | q2(13)<<13 | (dl>>2)<<26
__global__ __launch_bounds__(256) void k_pre(const int* __restrict__ ei,
                                             const float* __restrict__ ea,
                                             const float* __restrict__ ew1,
                                             const float* __restrict__ eb1,
                                             const float* __restrict__ ew2,
                                             const float* __restrict__ eb2,
                                             int* __restrict__ bcur,
                                             uint2* __restrict__ buf1,
                                             const float* __restrict__ x,
                                             const float* __restrict__ Wp,
                                             const float* __restrict__ bp,
                                             unsigned short* __restrict__ hb,
                                             unsigned char* __restrict__ h8) {
  __shared__ int lcnt[N_BUCKETS];
  __shared__ int gb[N_BUCKETS];
  if (blockIdx.x >= FILLA_BLOCKS) {
    // ---- projection half ----
    int idx = (blockIdx.x - FILLA_BLOCKS) * 256 + threadIdx.x;
    int n = idx >> 6, j = idx & 63;
    float acc = bp[j];
#pragma unroll
    for (int k = 0; k < 10; k++) acc += __builtin_nontemporal_load(&x[n * 10 + k]) * Wp[k * 64 + j];
    float r = fmaxf(acc, 0.f);
    hb[n * 64 + j] = f2bf(r);
    h8[n * 64 + j] = f2fp8(r);
    return;
  }
  // ---- fillA half ----
  for (int i = threadIdx.x; i < N_BUCKETS; i += 256) lcnt[i] = 0;
  __syncthreads();
  int base = blockIdx.x * CHUNK_A;
  uint2 rec[CHUNK_A / 256];
  int bk[CHUNK_A / 256], rk[CHUNK_A / 256];
#pragma unroll
  for (int k = 0; k < CHUNK_A / 256; k++) {
    int e = base + k * 256 + threadIdx.x;
    bk[k] = -1;
    if (e < N_EDGES) {
      int s = __builtin_nontemporal_load(&ei[e]);
      int d = __builtin_nontemporal_load(&ei[N_EDGES + e]);
      float a0 = __builtin_nontemporal_load(&ea[e * 3 + 0]);
      float a1 = __builtin_nontemporal_load(&ea[e * 3 + 1]);
      float a2 = __builtin_nontemporal_load(&ea[e * 3 + 2]);
      int q[3];
#pragma unroll
      for (int l = 0; l < 3; l++) {
        float z = eb2[l];
#pragma unroll
        for (int t = 0; t < 16; t++) {
          float hd = a0 * ew1[l * 48 + t] + a1 * ew1[l * 48 + 16 + t] +
                     a2 * ew1[l * 48 + 32 + t] + eb1[l * 16 + t];
          z += fmaxf(hd, 0.f) * ew2[l * 16 + t];
        }
        float w = 1.f / (1.f + __expf(-z));
        q[l] = __float2int_rn(w * 8191.f);
      }
      unsigned int dl = (unsigned int)(d & 255);
      rec[k].x = (unsigned int)s | ((unsigned int)q[0] << 17) | ((dl & 3u) << 30);
      rec[k].y = (unsigned int)q[1] | ((unsigned int)q[2] << 13) | ((dl >> 2) << 26);
      int b = d >> 8;
      bk[k] = b;
      rk[k] = atomicAdd(&lcnt[b], 1);
    }
  }
  __syncthreads();
  if (threadIdx.x < N_BUCKETS) {
    int c = lcnt[threadIdx.x];
    gb[threadIdx.x] = threadIdx.x * CAP_B + (c ? atomicAdd(&bcur[threadIdx.x], c) : 0);
  }
  __syncthreads();
#pragma unroll
  for (int k = 0; k < CHUNK_A / 256; k++)
    if (bk[k] >= 0) buf1[gb[bk[k]] + rk[k]] = rec[k];
}

// ---------- 2. fillB: block = bucket; LDS histogram + scan -> per-dst offsets,
// scatter into 3 per-layer 4B weight planes (src(17) | q13<<17);
// per-bucket degree-class-grouped node order. buf1 read twice -> cached loads.
__global__ __launch_bounds__(256) void k_fillB(const uint2* __restrict__ buf1,
                                               const int* __restrict__ bcur,
                                               unsigned int* __restrict__ pl0,
                                               unsigned int* __restrict__ pl1,
                                               unsigned int* __restrict__ pl2,
                                               int* __restrict__ aoffs,
                                               int* __restrict__ adeg,
                                               int* __restrict__ order) {
  __shared__ int lhist[256];
  __shared__ int lscan[256];
  __shared__ int lcls[8];
  __shared__ int lbase[8];
  int b = blockIdx.x;
  int t = threadIdx.x;
  int segbase = b * CAP_B;
  int cnt = bcur[b];
  lhist[t] = 0;
  if (t < 8) lcls[t] = 0;
  __syncthreads();
  for (int i = t; i < cnt; i += 256) {
    uint2 rec = buf1[segbase + i];
    int dl = (int)((rec.x >> 30) | (((rec.y >> 26) & 63u) << 2));
    atomicAdd(&lhist[dl], 1);
  }
  __syncthreads();
  int v = lhist[t];
  lscan[t] = v;
  __syncthreads();
#pragma unroll
  for (int off = 1; off < 256; off <<= 1) {
    int u = (t >= off) ? lscan[t - off] : 0;
    __syncthreads();
    lscan[t] += u;
    __syncthreads();
  }
  int excl = lscan[t] - v;
  int nid = b * 256 + t;
  int cls = 0, rank = 0;
  bool valid = nid < N_NODES;
  if (valid) {
    aoffs[nid] = segbase + excl;
    adeg[nid] = v;
    cls = min(v >> 2, 7);
    rank = atomicAdd(&lcls[cls], 1);
  }
  __syncthreads();
  if (t == 0) {
    int acc2 = 0;
#pragma unroll
    for (int c = 0; c < 8; c++) { lbase[c] = acc2; acc2 += lcls[c]; }
  }
  lhist[t] = segbase + excl;  // reuse as write cursor
  __syncthreads();
  if (valid) order[b * 256 + lbase[cls] + rank] = nid;
  for (int i = t; i < cnt; i += 256) {
    uint2 rec = buf1[segbase + i];
    int dl = (int)((rec.x >> 30) | (((rec.y >> 26) & 63u) << 2));
    int pos = atomicAdd(&lhist[dl], 1);
    unsigned int src = rec.x & 0x1FFFFu;
    pl0[pos] = src | ((rec.x >> 17) & 0x1FFFu) << 17;
    pl1[pos] = src | (rec.y & 0x1FFFu) << 17;
    pl2[pos] = src | ((rec.y >> 13) & 0x1FFFu) << 17;
  }
}

// ---------- 3. aggregation: 8 nodes/wave (class-grouped), fp8 gathers ----------
// SPLIT from mlp (R2/R15 lesson: gather TLP and MFMA don't mix in one wave).
// 4B plane record: src(17) | q13<<17. csr prefetch pipelined one batch ahead.
__global__ __launch_bounds__(256, 8) void k_agg(const unsigned int* __restrict__ pl,
                                                const int* __restrict__ aoffs,
                                                const int* __restrict__ adeg,
                                                const int* __restrict__ order,
                                                const unsigned char* __restrict__ h8in,
                                                unsigned short* __restrict__ ab) {
  int lane = threadIdx.x & 63;
  int sub = lane >> 3;   // node slot 0..7
  int jj = lane & 7;     // feature octet
  int gw = (blockIdx.x * 256 + threadIdx.x) >> 6;
  int idx = gw * 8 + sub;
  bool active = idx < N_NODES;
  int n = active ? order[idx] : 0;
  int start = active ? aoffs[n] : 0;
  int d = active ? adeg[n] : 0;
  const uint2* hrow = (const uint2*)h8in;  // row n at hrow[n*8 + jj] (8 fp8)
  float a0 = 0.f, a1 = 0.f, a2 = 0.f, a3 = 0.f;
  float a4 = 0.f, a5 = 0.f, a6 = 0.f, a7 = 0.f, ws = 0.f;
  int i = 0;
  if (d >= 4) {
    unsigned int c0 = pl[start + 0], c1 = pl[start + 1];
    unsigned int c2 = pl[start + 2], c3 = pl[start + 3];
    for (;;) {
      int nxt = i + 4;
      bool more = (nxt + 4 <= d);
      unsigned int m0, m1, m2, m3;
      if (more) {  // prefetch next batch before waiting on current gathers
        m0 = pl[start + nxt + 0]; m1 = pl[start + nxt + 1];
        m2 = pl[start + nxt + 2]; m3 = pl[start + nxt + 3];
      }
      uint2 g0 = hrow[(c0 & 0x1FFFFu) * 8 + jj];
      uint2 g1 = hrow[(c1 & 0x1FFFFu) * 8 + jj];
      uint2 g2 = hrow[(c2 & 0x1FFFFu) * 8 + jj];
      uint2 g3 = hrow[(c3 & 0x1FFFFu) * 8 + jj];
      float w0 = (float)(c0 >> 17) * (1.f / 8191.f);
      float w1 = (float)(c1 >> 17) * (1.f / 8191.f);
      float w2 = (float)(c2 >> 17) * (1.f / 8191.f);
      float w3 = (float)(c3 >> 17) * (1.f / 8191.f);
#pragma unroll
      for (int k = 0; k < 4; k++) {
        uint2 gg = (k == 0) ? g0 : (k == 1) ? g1 : (k == 2) ? g2 : g3;
        float w = (k == 0) ? w0 : (k == 1) ? w1 : (k == 2) ? w2 : w3;
        f32x2 p01 = __builtin_amdgcn_cvt_pk_f32_fp8(gg.x, false);
        f32x2 p23 = __builtin_amdgcn_cvt_pk_f32_fp8(gg.x, true);
        f32x2 p45 = __builtin_amdgcn_cvt_pk_f32_fp8(gg.y, false);
        f32x2 p67 = __builtin_amdgcn_cvt_pk_f32_fp8(gg.y, true);
        a0 += p01[0] * w; a1 += p01[1] * w;
        a2 += p23[0] * w; a3 += p23[1] * w;
        a4 += p45[0] * w; a5 += p45[1] * w;
        a6 += p67[0] * w; a7 += p67[1] * w;
      }
      ws += w0 + w1 + w2 + w3;
      i = nxt;
      if (!more) break;
      c0 = m0; c1 = m1; c2 = m2; c3 = m3;
    }
  }
  for (; i < d; ++i) {
    unsigned int c = pl[start + i];
    uint2 gg = hrow[(c & 0x1FFFFu) * 8 + jj];
    float w = (float)(c >> 17) * (1.f / 8191.f);
    f32x2 p01 = __builtin_amdgcn_cvt_pk_f32_fp8(gg.x, false);
    f32x2 p23 = __builtin_amdgcn_cvt_pk_f32_fp8(gg.x, true);
    f32x2 p45 = __builtin_amdgcn_cvt_pk_f32_fp8(gg.y, false);
    f32x2 p67 = __builtin_amdgcn_cvt_pk_f32_fp8(gg.y, true);
    a0 += p01[0] * w; a1 += p01[1] * w;
    a2 += p23[0] * w; a3 += p23[1] * w;
    a4 += p45[0] * w; a5 += p45[1] * w;
    a6 += p67[0] * w; a7 += p67[1] * w;
    ws += w;
  }
  if (active) {
    float inv = 1.f / fmaxf(ws, 1e-12f);
    uint4 o;
    o.x = (unsigned int)f2bf(a0 * inv) | ((unsigned int)f2bf(a1 * inv) << 16);
    o.y = (unsigned int)f2bf(a2 * inv) | ((unsigned int)f2bf(a3 * inv) << 16);
    o.z = (unsigned int)f2bf(a4 * inv) | ((unsigned int)f2bf(a5 * inv) << 16);
    o.w = (unsigned int)f2bf(a6 * inv) | ((unsigned int)f2bf(a7 * inv) << 16);
    ((uint4*)ab)[n * 8 + jj] = o;
  }
}

// ---------- 4. node MLP (MFMA) + residual(identity-MFMA) + LayerNorm [+ head] ----------
// C/D layout: col=lane&15, row=(lane>>4)*4+reg ; A/B frag: k=(lane>>4)*8+j
template <bool HEAD>
__global__ __launch_bounds__(256) void k_mlp(const float* __restrict__ nw,
                                             const float* __restrict__ nb,
                                             const float* __restrict__ g,
                                             const float* __restrict__ b,
                                             const unsigned short* __restrict__ hb_in,
                                             const unsigned short* __restrict__ ab_in,
                                             unsigned short* __restrict__ hbout,
                                             unsigned char* __restrict__ h8out,
                                             const float* __restrict__ hw1,
                                             const float* __restrict__ hb1,
                                             const float* __restrict__ hw2,
                                             const float* __restrict__ hb2,
                                             float* __restrict__ out) {
  __shared__ unsigned short lh[4][16 * 72];  // per-wave bf16 tile, stride 72
  int lane = threadIdx.x & 63;
  int n16 = lane & 15;
  int q = lane >> 4;
  int wv = threadIdx.x >> 6;
  int wid = (blockIdx.x * 256 + threadIdx.x) >> 6;
  int nwaves = gridDim.x * 4;

  bf16x8 bfr[4][4];
#pragma unroll
  for (int t = 0; t < 4; t++)
#pragma unroll
    for (int kc = 0; kc < 4; kc++) {
      bf16x8 v;
#pragma unroll
      for (int jj = 0; jj < 8; jj++) {
        int k = kc * 32 + q * 8 + jj;
        v[jj] = (short)f2bf(nw[k * 64 + t * 16 + n16]);
      }
      bfr[t][kc] = v;
    }
  // identity selector fragments: E_p[k][n] = (k == n+16p)
  bf16x8 eye[2];
#pragma unroll
  for (int p = 0; p < 2; p++) {
    bf16x8 v;
#pragma unroll
    for (int jj = 0; jj < 8; jj++)
      v[jj] = ((q * 8 + jj) == (n16 + 16 * p)) ? (short)0x3F80 : (short)0;
    eye[p] = v;
  }
  float nbv[4], gv[4], bv[4];
#pragma unroll
  for (int t = 0; t < 4; t++) {
    nbv[t] = nb[t * 16 + n16];
    gv[t] = g[t * 16 + n16];
    bv[t] = b[t * 16 + n16];
  }
  // head weights (layer 2 only)
  bf16x8 hfr[2][2];
  float hb1v[2], hw2v[2], hb2v = 0.f;
  if (HEAD) {
#pragma unroll
    for (int kc = 0; kc < 2; kc++)
#pragma unroll
      for (int tl = 0; tl < 2; tl++) {
        bf16x8 v;
#pragma unroll
        for (int jj = 0; jj < 8; jj++)
          v[jj] = (short)f2bf(hw1[(kc * 32 + q * 8 + jj) * 32 + tl * 16 + n16]);
        hfr[kc][tl] = v;
      }
#pragma unroll
    for (int tl = 0; tl < 2; tl++) {
      hb1v[tl] = hb1[tl * 16 + n16];
      hw2v[tl] = hw2[tl * 16 + n16];
    }
    hb2v = hb2[0];
  }

  for (int s = wid; s < N_STRIPS; s += nwaves) {
    int n0 = s * 16;
    f32x4 acc[4] = {{0.f, 0.f, 0.f, 0.f}, {0.f, 0.f, 0.f, 0.f},
                    {0.f, 0.f, 0.f, 0.f}, {0.f, 0.f, 0.f, 0.f}};
    bf16x8 afr[4];
#pragma unroll
    for (int kc = 0; kc < 4; kc++) {
      const unsigned short* base = (kc < 2) ? hb_in : ab_in;
      afr[kc] = __builtin_nontemporal_load(
          (const bf16x8*)(base + (size_t)(n0 + n16) * 64 + (kc & 1) * 32 + q * 8));
#pragma unroll
      for (int t = 0; t < 4; t++)
        acc[t] = __builtin_amdgcn_mfma_f32_16x16x32_bf16(afr[kc], bfr[t][kc], acc[t], 0, 0, 0);
    }
    // residual h in C layout via identity MFMA (exact)
    f32x4 rres[4];
#pragma unroll
    for (int t = 0; t < 4; t++) {
      f32x4 z = {0.f, 0.f, 0.f, 0.f};
      rres[t] = __builtin_amdgcn_mfma_f32_16x16x32_bf16(afr[t >> 1], eye[t & 1], z, 0, 0, 0);
    }
    float r[4][4];
    float p[4], p2[4];
#pragma unroll
    for (int rg = 0; rg < 4; rg++) { p[rg] = 0.f; p2[rg] = 0.f; }
#pragma unroll
    for (int t = 0; t < 4; t++)
#pragma unroll
      for (int rg = 0; rg < 4; rg++) {
        float rr = rres[t][rg] + fmaxf(acc[t][rg] + nbv[t], 0.f);
        r[t][rg] = rr;
        p[rg] += rr;
        p2[rg] += rr * rr;
      }
#pragma unroll
    for (int rg = 0; rg < 4; rg++)
#pragma unroll
      for (int off = 1; off < 16; off <<= 1) {
        p[rg] += __shfl_xor(p[rg], off);
        p2[rg] += __shfl_xor(p2[rg], off);
      }
#pragma unroll
    for (int rg = 0; rg < 4; rg++) {
      float mu = p[rg] * (1.f / 64.f);
      float var = p2[rg] * (1.f / 64.f) - mu * mu;
      float rs = rsqrtf(fmaxf(var, 0.f) + 1e-5f);
      int row = n0 + q * 4 + rg;
#pragma unroll
      for (int t = 0; t < 4; t++) {
        float o = (r[t][rg] - mu) * rs * gv[t] + bv[t];
        unsigned short ob = f2bf(o);
        hbout[row * 64 + t * 16 + n16] = ob;
        h8out[row * 64 + t * 16 + n16] = f2fp8(o);
        if (HEAD) lh[wv][(q * 4 + rg) * 72 + t * 16 + n16] = ob;
      }
    }
    if (HEAD) {
      asm volatile("s_waitcnt lgkmcnt(0)" ::: "memory");  // wave-local LDS RAW
      f32x4 hacc[2] = {{0.f, 0.f, 0.f, 0.f}, {0.f, 0.f, 0.f, 0.f}};
#pragma unroll
      for (int kc = 0; kc < 2; kc++) {
        bf16x8 ha = *(const bf16x8*)&lh[wv][n16 * 72 + kc * 32 + q * 8];
#pragma unroll
        for (int tl = 0; tl < 2; tl++)
          hacc[tl] = __builtin_amdgcn_mfma_f32_16x16x32_bf16(ha, hfr[kc][tl], hacc[tl], 0, 0, 0);
      }
#pragma unroll
      for (int rg = 0; rg < 4; rg++) {
        float sres = fmaxf(hacc[0][rg] + hb1v[0], 0.f) * hw2v[0] +
                     fmaxf(hacc[1][rg] + hb1v[1], 0.f) * hw2v[1];
#pragma unroll
        for (int off = 1; off < 16; off <<= 1) sres += __shfl_xor(sres, off);
        if (n16 == 0) out[n0 + q * 4 + rg] = sres + hb2v;
      }
    }
  }
}

// ---------- launch ----------
static inline size_t align256(size_t x) { return (x + 255) & ~size_t(255); }

extern "C" void kernel_launch(void* const* d_in, const int* in_sizes, int n_in,
                              void* d_out, int out_size, void* d_ws, size_t ws_size,
                              hipStream_t stream) {
  const float* x   = (const float*)d_in[0];
  const int*   ei  = (const int*)d_in[1];
  const float* ea  = (const float*)d_in[2];
  const float* Wp  = (const float*)d_in[3];
  const float* bp  = (const float*)d_in[4];
  const float* ew1 = (const float*)d_in[5];
  const float* eb1 = (const float*)d_in[6];
  const float* ew2 = (const float*)d_in[7];
  const float* eb2 = (const float*)d_in[8];
  const float* nw  = (const float*)d_in[9];
  const float* nb  = (const float*)d_in[10];
  const float* lng = (const float*)d_in[11];
  const float* lnb = (const float*)d_in[12];
  const float* hw1 = (const float*)d_in[13];
  const float* hb1 = (const float*)d_in[14];
  const float* hw2 = (const float*)d_in[15];
  const float* hb2 = (const float*)d_in[16];
  float* out = (float*)d_out;

  char* ws = (char*)d_ws;
  size_t off = 0;
  unsigned short* hb0  = (unsigned short*)(ws + off); off = align256(off + (size_t)N_NODES * 64 * 2);
  unsigned short* hb1b = (unsigned short*)(ws + off); off = align256(off + (size_t)N_NODES * 64 * 2);
  unsigned short* ab   = (unsigned short*)(ws + off); off = align256(off + (size_t)N_NODES * 64 * 2);
  unsigned char* h8_0  = (unsigned char*)(ws + off); off = align256(off + (size_t)N_NODES * 64);
  unsigned char* h8_1  = (unsigned char*)(ws + off); off = align256(off + (size_t)N_NODES * 64);
  uint2* buf1 = (uint2*)(ws + off); off = align256(off + (size_t)N_BUCKETS * CAP_B * 8);
  unsigned int* pl0 = (unsigned int*)(ws + off); off = align256(off + (size_t)N_BUCKETS * CAP_B * 4);
  unsigned int* pl1 = (unsigned int*)(ws + off); off = align256(off + (size_t)N_BUCKETS * CAP_B * 4);
  unsigned int* pl2 = (unsigned int*)(ws + off); off = align256(off + (size_t)N_BUCKETS * CAP_B * 4);
  int* aoffs  = (int*)(ws + off); off = align256(off + (size_t)N_NODES * 4);
  int* adeg   = (int*)(ws + off); off = align256(off + (size_t)N_NODES * 4);
  int* order  = (int*)(ws + off); off = align256(off + (size_t)N_NODES * 4);
  int* bcur   = (int*)(ws + off); off = align256(off + 1024);

  (void)hipMemsetAsync(bcur, 0, N_BUCKETS * 4, stream);
  k_pre<<<FILLA_BLOCKS + PROJ_BLOCKS, 256, 0, stream>>>(ei, ea, ew1, eb1, ew2, eb2, bcur, buf1,
                                                        x, Wp, bp, hb0, h8_0);
  k_fillB<<<N_BUCKETS, 256, 0, stream>>>(buf1, bcur, pl0, pl1, pl2, aoffs, adeg, order);

  const int aggGrid = (N_NODES + 31) / 32;  // 8 nodes/wave, 4 waves/block
  const int mlpGrid = 392;

  // layer 0
  k_agg<<<aggGrid, 256, 0, stream>>>(pl0, aoffs, adeg, order, h8_0, ab);
  k_mlp<false><<<mlpGrid, 256, 0, stream>>>(nw + 0 * 8192, nb + 0 * 64, lng + 0 * 64, lnb + 0 * 64,
                                            hb0, ab, hb1b, h8_1, hw1, hb1, hw2, hb2, out);
  // layer 1
  k_agg<<<aggGrid, 256, 0, stream>>>(pl1, aoffs, adeg, order, h8_1, ab);
  k_mlp<false><<<mlpGrid, 256, 0, stream>>>(nw + 1 * 8192, nb + 1 * 64, lng + 1 * 64, lnb + 1 * 64,
                                            hb1b, ab, hb0, h8_0, hw1, hb1, hw2, hb2, out);
  // layer 2 + fused head
  k_agg<<<aggGrid, 256, 0, stream>>>(pl2, aoffs, adeg, order, h8_0, ab);
  k_mlp<true><<<mlpGrid, 256, 0, stream>>>(nw + 2 * 8192, nb + 2 * 64, lng + 2 * 64, lnb + 2 * 64,
                                           hb0, ab, hb1b, h8_1, hw1, hb1, hw2, hb2, out);
}

// Round 17
// 219.630 us; speedup vs baseline: 1.1369x; 1.0172x over previous
//
#include <hip/hip_runtime.h>
#include <math.h>

#define N_NODES 50000
#define N_EDGES 800000
#define N_STRIPS 3125     // 50000 / 16
#define N_BUCKETS 196     // ceil(50000/256); bucket = dst>>8
#define CAP_B 6144        // fixed records per bucket segment
#define CHUNK_A 2048      // edges per fillA block
#define FILLA_BLOCKS 391  // ceil(800000/2048)
#define PROJ_BLOCKS 12500 // 50000*64/256

typedef __attribute__((ext_vector_type(8))) short bf16x8;
typedef __attribute__((ext_vector_type(4))) float f32x4;
typedef __attribute__((ext_vector_type(2))) float f32x2;

// ---------- helpers ----------
__device__ __forceinline__ unsigned short f2bf(float f) {  // RNE f32->bf16
  unsigned int u = __float_as_uint(f);
  u += 0x7FFFu + ((u >> 16) & 1u);
  return (unsigned short)(u >> 16);
}
__device__ __forceinline__ unsigned char f2fp8(float f) {  // e4m3fn (OCP) encode
  return (unsigned char)(__builtin_amdgcn_cvt_pk_fp8_f32(f, f, 0, false) & 0xFF);
}

// ---------- 1. fused: fillA (blocks [0,391)) + input projection (rest) ----------
// 8B buf1/csr record: x = src(17) | q0(13)<<17 | (dl&3)<<30 ; y = q1(13) | q2(13)<<13 | (dl>>2)<<26
__global__ __launch_bounds__(256) void k_pre(const int* __restrict__ ei,
                                             const float* __restrict__ ea,
                                             const float* __restrict__ ew1,
                                             const float* __restrict__ eb1,
                                             const float* __restrict__ ew2,
                                             const float* __restrict__ eb2,
                                             int* __restrict__ bcur,
                                             uint2* __restrict__ buf1,
                                             const float* __restrict__ x,
                                             const float* __restrict__ Wp,
                                             const float* __restrict__ bp,
                                             unsigned short* __restrict__ hb,
                                             unsigned char* __restrict__ h8) {
  __shared__ int lcnt[N_BUCKETS];
  __shared__ int gb[N_BUCKETS];
  if (blockIdx.x >= FILLA_BLOCKS) {
    // ---- projection half ----
    int idx = (blockIdx.x - FILLA_BLOCKS) * 256 + threadIdx.x;
    int n = idx >> 6, j = idx & 63;
    float acc = bp[j];
#pragma unroll
    for (int k = 0; k < 10; k++) acc += __builtin_nontemporal_load(&x[n * 10 + k]) * Wp[k * 64 + j];
    float r = fmaxf(acc, 0.f);
    hb[n * 64 + j] = f2bf(r);
    h8[n * 64 + j] = f2fp8(r);
    return;
  }
  // ---- fillA half ----
  for (int i = threadIdx.x; i < N_BUCKETS; i += 256) lcnt[i] = 0;
  __syncthreads();
  int base = blockIdx.x * CHUNK_A;
  uint2 rec[CHUNK_A / 256];
  int bk[CHUNK_A / 256], rk[CHUNK_A / 256];
#pragma unroll
  for (int k = 0; k < CHUNK_A / 256; k++) {
    int e = base + k * 256 + threadIdx.x;
    bk[k] = -1;
    if (e < N_EDGES) {
      int s = __builtin_nontemporal_load(&ei[e]);
      int d = __builtin_nontemporal_load(&ei[N_EDGES + e]);
      float a0 = __builtin_nontemporal_load(&ea[e * 3 + 0]);
      float a1 = __builtin_nontemporal_load(&ea[e * 3 + 1]);
      float a2 = __builtin_nontemporal_load(&ea[e * 3 + 2]);
      int q[3];
#pragma unroll
      for (int l = 0; l < 3; l++) {
        float z = eb2[l];
#pragma unroll
        for (int t = 0; t < 16; t++) {
          float hd = a0 * ew1[l * 48 + t] + a1 * ew1[l * 48 + 16 + t] +
                     a2 * ew1[l * 48 + 32 + t] + eb1[l * 16 + t];
          z += fmaxf(hd, 0.f) * ew2[l * 16 + t];
        }
        float w = 1.f / (1.f + __expf(-z));
        q[l] = __float2int_rn(w * 8191.f);
      }
      unsigned int dl = (unsigned int)(d & 255);
      rec[k].x = (unsigned int)s | ((unsigned int)q[0] << 17) | ((dl & 3u) << 30);
      rec[k].y = (unsigned int)q[1] | ((unsigned int)q[2] << 13) | ((dl >> 2) << 26);
      int b = d >> 8;
      bk[k] = b;
      rk[k] = atomicAdd(&lcnt[b], 1);
    }
  }
  __syncthreads();
  if (threadIdx.x < N_BUCKETS) {
    int c = lcnt[threadIdx.x];
    gb[threadIdx.x] = threadIdx.x * CAP_B + (c ? atomicAdd(&bcur[threadIdx.x], c) : 0);
  }
  __syncthreads();
#pragma unroll
  for (int k = 0; k < CHUNK_A / 256; k++)
    if (bk[k] >= 0) buf1[gb[bk[k]] + rk[k]] = rec[k];
}

// ---------- 2. fillB: block = bucket; LDS histogram + scan -> per-dst offsets,
// scatter into private csr window; per-bucket degree-class-grouped node order.
// buf1 read twice -> plain cached loads (R13 lesson: NT loses reuse).
__global__ __launch_bounds__(256) void k_fillB(const uint2* __restrict__ buf1,
                                               const int* __restrict__ bcur,
                                               uint2* __restrict__ csr,
                                               int* __restrict__ aoffs,
                                               int* __restrict__ adeg,
                                               int* __restrict__ order) {
  __shared__ int lhist[256];
  __shared__ int lscan[256];
  __shared__ int lcls[8];
  __shared__ int lbase[8];
  int b = blockIdx.x;
  int t = threadIdx.x;
  int segbase = b * CAP_B;
  int cnt = bcur[b];
  lhist[t] = 0;
  if (t < 8) lcls[t] = 0;
  __syncthreads();
  for (int i = t; i < cnt; i += 256) {
    uint2 rec = buf1[segbase + i];
    int dl = (int)((rec.x >> 30) | (((rec.y >> 26) & 63u) << 2));
    atomicAdd(&lhist[dl], 1);
  }
  __syncthreads();
  int v = lhist[t];
  lscan[t] = v;
  __syncthreads();
#pragma unroll
  for (int off = 1; off < 256; off <<= 1) {
    int u = (t >= off) ? lscan[t - off] : 0;
    __syncthreads();
    lscan[t] += u;
    __syncthreads();
  }
  int excl = lscan[t] - v;
  int nid = b * 256 + t;
  int cls = 0, rank = 0;
  bool valid = nid < N_NODES;
  if (valid) {
    aoffs[nid] = segbase + excl;
    adeg[nid] = v;
    cls = min(v >> 2, 7);
    rank = atomicAdd(&lcls[cls], 1);
  }
  __syncthreads();
  if (t == 0) {
    int acc2 = 0;
#pragma unroll
    for (int c = 0; c < 8; c++) { lbase[c] = acc2; acc2 += lcls[c]; }
  }
  lhist[t] = segbase + excl;  // reuse as write cursor
  __syncthreads();
  if (valid) order[b * 256 + lbase[cls] + rank] = nid;
  for (int i = t; i < cnt; i += 256) {
    uint2 rec = buf1[segbase + i];
    int dl = (int)((rec.x >> 30) | (((rec.y >> 26) & 63u) << 2));
    int pos = atomicAdd(&lhist[dl], 1);
    csr[pos] = rec;
  }
}

template <int LI>
__device__ __forceinline__ float decw(uint2 c) {
  unsigned int q = (LI == 0) ? ((c.x >> 17) & 0x1FFFu)
                 : (LI == 1) ? (c.y & 0x1FFFu)
                             : ((c.y >> 13) & 0x1FFFu);
  return (float)q * (1.f / 8191.f);
}

// ---------- 3. aggregation: 8 nodes/wave (class-grouped), fp8 gathers ----------
// SPLIT from mlp (R2/R15 lesson). Packed f32x2 accumulation -> v_pk_fma_f32
// halves the FMA count (agg is VALU-issue-bound, ~9us/layer at scalar FMA).
template <int LI>
__global__ __launch_bounds__(256, 8) void k_agg(const uint2* __restrict__ csr,
                                                const int* __restrict__ aoffs,
                                                const int* __restrict__ adeg,
                                                const int* __restrict__ order,
                                                const unsigned char* __restrict__ h8in,
                                                unsigned short* __restrict__ ab) {
  int lane = threadIdx.x & 63;
  int sub = lane >> 3;   // node slot 0..7
  int jj = lane & 7;     // feature octet
  int gw = (blockIdx.x * 256 + threadIdx.x) >> 6;
  int idx = gw * 8 + sub;
  bool active = idx < N_NODES;
  int n = active ? order[idx] : 0;
  int start = active ? aoffs[n] : 0;
  int d = active ? adeg[n] : 0;
  const uint2* hrow = (const uint2*)h8in;  // row n at hrow[n*8 + jj] (8 fp8)
  f32x2 A01 = {0.f, 0.f}, A23 = {0.f, 0.f}, A45 = {0.f, 0.f}, A67 = {0.f, 0.f};
  float ws = 0.f;
  int i = 0;
  if (d >= 4) {
    uint2 c0 = csr[start + 0], c1 = csr[start + 1];
    uint2 c2 = csr[start + 2], c3 = csr[start + 3];
    for (;;) {
      int nxt = i + 4;
      bool more = (nxt + 4 <= d);
      uint2 m0, m1, m2, m3;
      if (more) {  // prefetch next batch before waiting on current gathers
        m0 = csr[start + nxt + 0]; m1 = csr[start + nxt + 1];
        m2 = csr[start + nxt + 2]; m3 = csr[start + nxt + 3];
      }
      uint2 g0 = hrow[(c0.x & 0x1FFFFu) * 8 + jj];
      uint2 g1 = hrow[(c1.x & 0x1FFFFu) * 8 + jj];
      uint2 g2 = hrow[(c2.x & 0x1FFFFu) * 8 + jj];
      uint2 g3 = hrow[(c3.x & 0x1FFFFu) * 8 + jj];
      float w0 = decw<LI>(c0), w1 = decw<LI>(c1), w2 = decw<LI>(c2), w3 = decw<LI>(c3);
#pragma unroll
      for (int k = 0; k < 4; k++) {
        uint2 gg = (k == 0) ? g0 : (k == 1) ? g1 : (k == 2) ? g2 : g3;
        float w = (k == 0) ? w0 : (k == 1) ? w1 : (k == 2) ? w2 : w3;
        f32x2 w2v = {w, w};
        A01 += __builtin_amdgcn_cvt_pk_f32_fp8(gg.x, false) * w2v;
        A23 += __builtin_amdgcn_cvt_pk_f32_fp8(gg.x, true) * w2v;
        A45 += __builtin_amdgcn_cvt_pk_f32_fp8(gg.y, false) * w2v;
        A67 += __builtin_amdgcn_cvt_pk_f32_fp8(gg.y, true) * w2v;
      }
      ws += w0 + w1 + w2 + w3;
      i = nxt;
      if (!more) break;
      c0 = m0; c1 = m1; c2 = m2; c3 = m3;
    }
  }
  for (; i < d; ++i) {
    uint2 c = csr[start + i];
    uint2 gg = hrow[(c.x & 0x1FFFFu) * 8 + jj];
    float w = decw<LI>(c);
    f32x2 w2v = {w, w};
    A01 += __builtin_amdgcn_cvt_pk_f32_fp8(gg.x, false) * w2v;
    A23 += __builtin_amdgcn_cvt_pk_f32_fp8(gg.x, true) * w2v;
    A45 += __builtin_amdgcn_cvt_pk_f32_fp8(gg.y, false) * w2v;
    A67 += __builtin_amdgcn_cvt_pk_f32_fp8(gg.y, true) * w2v;
    ws += w;
  }
  if (active) {
    float inv = 1.f / fmaxf(ws, 1e-12f);
    f32x2 inv2 = {inv, inv};
    A01 *= inv2; A23 *= inv2; A45 *= inv2; A67 *= inv2;
    uint4 o;
    o.x = (unsigned int)f2bf(A01[0]) | ((unsigned int)f2bf(A01[1]) << 16);
    o.y = (unsigned int)f2bf(A23[0]) | ((unsigned int)f2bf(A23[1]) << 16);
    o.z = (unsigned int)f2bf(A45[0]) | ((unsigned int)f2bf(A45[1]) << 16);
    o.w = (unsigned int)f2bf(A67[0]) | ((unsigned int)f2bf(A67[1]) << 16);
    ((uint4*)ab)[n * 8 + jj] = o;
  }
}

// ---------- 4. node MLP (MFMA) + residual(identity-MFMA) + LayerNorm [+ head] ----------
// C/D layout: col=lane&15, row=(lane>>4)*4+reg ; A/B frag: k=(lane>>4)*8+j
template <bool HEAD>
__global__ __launch_bounds__(256) void k_mlp(const float* __restrict__ nw,
                                             const float* __restrict__ nb,
                                             const float* __restrict__ g,
                                             const float* __restrict__ b,
                                             const unsigned short* __restrict__ hb_in,
                                             const unsigned short* __restrict__ ab_in,
                                             unsigned short* __restrict__ hbout,
                                             unsigned char* __restrict__ h8out,
                                             const float* __restrict__ hw1,
                                             const float* __restrict__ hb1,
                                             const float* __restrict__ hw2,
                                             const float* __restrict__ hb2,
                                             float* __restrict__ out) {
  __shared__ unsigned short lh[4][16 * 72];  // per-wave bf16 tile, stride 72
  int lane = threadIdx.x & 63;
  int n16 = lane & 15;
  int q = lane >> 4;
  int wv = threadIdx.x >> 6;
  int wid = (blockIdx.x * 256 + threadIdx.x) >> 6;
  int nwaves = gridDim.x * 4;

  bf16x8 bfr[4][4];
#pragma unroll
  for (int t = 0; t < 4; t++)
#pragma unroll
    for (int kc = 0; kc < 4; kc++) {
      bf16x8 v;
#pragma unroll
      for (int jj = 0; jj < 8; jj++) {
        int k = kc * 32 + q * 8 + jj;
        v[jj] = (short)f2bf(nw[k * 64 + t * 16 + n16]);
      }
      bfr[t][kc] = v;
    }
  // identity selector fragments: E_p[k][n] = (k == n+16p)
  bf16x8 eye[2];
#pragma unroll
  for (int p = 0; p < 2; p++) {
    bf16x8 v;
#pragma unroll
    for (int jj = 0; jj < 8; jj++)
      v[jj] = ((q * 8 + jj) == (n16 + 16 * p)) ? (short)0x3F80 : (short)0;
    eye[p] = v;
  }
  float nbv[4], gv[4], bv[4];
#pragma unroll
  for (int t = 0; t < 4; t++) {
    nbv[t] = nb[t * 16 + n16];
    gv[t] = g[t * 16 + n16];
    bv[t] = b[t * 16 + n16];
  }
  // head weights (layer 2 only)
  bf16x8 hfr[2][2];
  float hb1v[2], hw2v[2], hb2v = 0.f;
  if (HEAD) {
#pragma unroll
    for (int kc = 0; kc < 2; kc++)
#pragma unroll
      for (int tl = 0; tl < 2; tl++) {
        bf16x8 v;
#pragma unroll
        for (int jj = 0; jj < 8; jj++)
          v[jj] = (short)f2bf(hw1[(kc * 32 + q * 8 + jj) * 32 + tl * 16 + n16]);
        hfr[kc][tl] = v;
      }
#pragma unroll
    for (int tl = 0; tl < 2; tl++) {
      hb1v[tl] = hb1[tl * 16 + n16];
      hw2v[tl] = hw2[tl * 16 + n16];
    }
    hb2v = hb2[0];
  }

  for (int s = wid; s < N_STRIPS; s += nwaves) {
    int n0 = s * 16;
    f32x4 acc[4] = {{0.f, 0.f, 0.f, 0.f}, {0.f, 0.f, 0.f, 0.f},
                    {0.f, 0.f, 0.f, 0.f}, {0.f, 0.f, 0.f, 0.f}};
    bf16x8 afr[4];
#pragma unroll
    for (int kc = 0; kc < 4; kc++) {
      const unsigned short* base = (kc < 2) ? hb_in : ab_in;
      afr[kc] = __builtin_nontemporal_load(
          (const bf16x8*)(base + (size_t)(n0 + n16) * 64 + (kc & 1) * 32 + q * 8));
#pragma unroll
      for (int t = 0; t < 4; t++)
        acc[t] = __builtin_amdgcn_mfma_f32_16x16x32_bf16(afr[kc], bfr[t][kc], acc[t], 0, 0, 0);
    }
    // residual h in C layout via identity MFMA (exact)
    f32x4 rres[4];
#pragma unroll
    for (int t = 0; t < 4; t++) {
      f32x4 z = {0.f, 0.f, 0.f, 0.f};
      rres[t] = __builtin_amdgcn_mfma_f32_16x16x32_bf16(afr[t >> 1], eye[t & 1], z, 0, 0, 0);
    }
    float r[4][4];
    float p[4], p2[4];
#pragma unroll
    for (int rg = 0; rg < 4; rg++) { p[rg] = 0.f; p2[rg] = 0.f; }
#pragma unroll
    for (int t = 0; t < 4; t++)
#pragma unroll
      for (int rg = 0; rg < 4; rg++) {
        float rr = rres[t][rg] + fmaxf(acc[t][rg] + nbv[t], 0.f);
        r[t][rg] = rr;
        p[rg] += rr;
        p2[rg] += rr * rr;
      }
#pragma unroll
    for (int rg = 0; rg < 4; rg++)
#pragma unroll
      for (int off = 1; off < 16; off <<= 1) {
        p[rg] += __shfl_xor(p[rg], off);
        p2[rg] += __shfl_xor(p2[rg], off);
      }
#pragma unroll
    for (int rg = 0; rg < 4; rg++) {
      float mu = p[rg] * (1.f / 64.f);
      float var = p2[rg] * (1.f / 64.f) - mu * mu;
      float rs = rsqrtf(fmaxf(var, 0.f) + 1e-5f);
      int row = n0 + q * 4 + rg;
#pragma unroll
      for (int t = 0; t < 4; t++) {
        float o = (r[t][rg] - mu) * rs * gv[t] + bv[t];
        unsigned short ob = f2bf(o);
        hbout[row * 64 + t * 16 + n16] = ob;
        h8out[row * 64 + t * 16 + n16] = f2fp8(o);
        if (HEAD) lh[wv][(q * 4 + rg) * 72 + t * 16 + n16] = ob;
      }
    }
    if (HEAD) {
      asm volatile("s_waitcnt lgkmcnt(0)" ::: "memory");  // wave-local LDS RAW
      f32x4 hacc[2] = {{0.f, 0.f, 0.f, 0.f}, {0.f, 0.f, 0.f, 0.f}};
#pragma unroll
      for (int kc = 0; kc < 2; kc++) {
        bf16x8 ha = *(const bf16x8*)&lh[wv][n16 * 72 + kc * 32 + q * 8];
#pragma unroll
        for (int tl = 0; tl < 2; tl++)
          hacc[tl] = __builtin_amdgcn_mfma_f32_16x16x32_bf16(ha, hfr[kc][tl], hacc[tl], 0, 0, 0);
      }
#pragma unroll
      for (int rg = 0; rg < 4; rg++) {
        float sres = fmaxf(hacc[0][rg] + hb1v[0], 0.f) * hw2v[0] +
                     fmaxf(hacc[1][rg] + hb1v[1], 0.f) * hw2v[1];
#pragma unroll
        for (int off = 1; off < 16; off <<= 1) sres += __shfl_xor(sres, off);
        if (n16 == 0) out[n0 + q * 4 + rg] = sres + hb2v;
      }
    }
  }
}

// ---------- launch ----------
static inline size_t align256(size_t x) { return (x + 255) & ~size_t(255); }

extern "C" void kernel_launch(void* const* d_in, const int* in_sizes, int n_in,
                              void* d_out, int out_size, void* d_ws, size_t ws_size,
                              hipStream_t stream) {
  const float* x   = (const float*)d_in[0];
  const int*   ei  = (const int*)d_in[1];
  const float* ea  = (const float*)d_in[2];
  const float* Wp  = (const float*)d_in[3];
  const float* bp  = (const float*)d_in[4];
  const float* ew1 = (const float*)d_in[5];
  const float* eb1 = (const float*)d_in[6];
  const float* ew2 = (const float*)d_in[7];
  const float* eb2 = (const float*)d_in[8];
  const float* nw  = (const float*)d_in[9];
  const float* nb  = (const float*)d_in[10];
  const float* lng = (const float*)d_in[11];
  const float* lnb = (const float*)d_in[12];
  const float* hw1 = (const float*)d_in[13];
  const float* hb1 = (const float*)d_in[14];
  const float* hw2 = (const float*)d_in[15];
  const float* hb2 = (const float*)d_in[16];
  float* out = (float*)d_out;

  char* ws = (char*)d_ws;
  size_t off = 0;
  unsigned short* hb0  = (unsigned short*)(ws + off); off = align256(off + (size_t)N_NODES * 64 * 2);
  unsigned short* hb1b = (unsigned short*)(ws + off); off = align256(off + (size_t)N_NODES * 64 * 2);
  unsigned short* ab   = (unsigned short*)(ws + off); off = align256(off + (size_t)N_NODES * 64 * 2);
  unsigned char* h8_0  = (unsigned char*)(ws + off); off = align256(off + (size_t)N_NODES * 64);
  unsigned char* h8_1  = (unsigned char*)(ws + off); off = align256(off + (size_t)N_NODES * 64);
  uint2* csr  = (uint2*)(ws + off); off = align256(off + (size_t)N_BUCKETS * CAP_B * 8);
  uint2* buf1 = (uint2*)(ws + off); off = align256(off + (size_t)N_BUCKETS * CAP_B * 8);
  int* aoffs  = (int*)(ws + off); off = align256(off + (size_t)N_NODES * 4);
  int* adeg   = (int*)(ws + off); off = align256(off + (size_t)N_NODES * 4);
  int* order  = (int*)(ws + off); off = align256(off + (size_t)N_NODES * 4);
  int* bcur   = (int*)(ws + off); off = align256(off + 1024);

  (void)hipMemsetAsync(bcur, 0, N_BUCKETS * 4, stream);
  k_pre<<<FILLA_BLOCKS + PROJ_BLOCKS, 256, 0, stream>>>(ei, ea, ew1, eb1, ew2, eb2, bcur, buf1,
                                                        x, Wp, bp, hb0, h8_0);
  k_fillB<<<N_BUCKETS, 256, 0, stream>>>(buf1, bcur, csr, aoffs, adeg, order);

  const int aggGrid = (N_NODES + 31) / 32;  // 8 nodes/wave, 4 waves/block
  const int mlpGrid = 392;

  // layer 0
  k_agg<0><<<aggGrid, 256, 0, stream>>>(csr, aoffs, adeg, order, h8_0, ab);
  k_mlp<false><<<mlpGrid, 256, 0, stream>>>(nw + 0 * 8192, nb + 0 * 64, lng + 0 * 64, lnb + 0 * 64,
                                            hb0, ab, hb1b, h8_1, hw1, hb1, hw2, hb2, out);
  // layer 1
  k_agg<1><<<aggGrid, 256, 0, stream>>>(csr, aoffs, adeg, order, h8_1, ab);
  k_mlp<false><<<mlpGrid, 256, 0, stream>>>(nw + 1 * 8192, nb + 1 * 64, lng + 1 * 64, lnb + 1 * 64,
                                            hb1b, ab, hb0, h8_0, hw1, hb1, hw2, hb2, out);
  // layer 2 + fused head
  k_agg<2><<<aggGrid, 256, 0, stream>>>(csr, aoffs, adeg, order, h8_0, ab);
  k_mlp<true><<<mlpGrid, 256, 0, stream>>>(nw + 2 * 8192, nb + 2 * 64, lng + 2 * 64, lnb + 2 * 64,
                                           hb0, ab, hb1b, h8_1, hw1, hb1, hw2, hb2, out);
}